// Round 4
// baseline (233.499 us; speedup 1.0000x reference)
//
#include <hip/hip_runtime.h>

#define GN 4096
#define KS 8          // split-K factor for A@h GEMM

typedef __attribute__((ext_vector_type(8))) short bf16x8_t;
typedef __attribute__((ext_vector_type(4))) float f32x4_t;

// fp32 -> bf16 RNE, explicit bit ops.
__device__ __forceinline__ unsigned rne(unsigned u) {
    return u + 0x7fffu + ((u >> 16) & 1u);
}
__device__ __forceinline__ unsigned pkbf(float x, float y) {
    union { float f; unsigned u; } a, b; a.f = x; b.f = y;
    return (rne(a.u) >> 16) | (rne(b.u) & 0xffff0000u);   // low short = bf16(x)
}
__device__ __forceinline__ bf16x8_t cvt8(float4 a0, float4 a1) {
    union { unsigned u[4]; bf16x8_t v; } r;
    r.u[0] = pkbf(a0.x, a0.y);
    r.u[1] = pkbf(a0.z, a0.w);
    r.u[2] = pkbf(a1.x, a1.y);
    r.u[3] = pkbf(a1.z, a1.w);
    return r.v;
}
__device__ __forceinline__ short f2bf(float x) {
    union { float f; unsigned u; } c; c.f = x;
    return (short)(rne(c.u) >> 16);
}
__device__ __forceinline__ float bf2f(short s) {
    union { unsigned u; float f; } c; c.u = ((unsigned)(unsigned short)s) << 16;
    return c.f;
}
// split 8 fp32 into hi (bf16 RNE) and lo (bf16 of residual): ~16-bit mantissa total
__device__ __forceinline__ void split8(float4 a0, float4 a1, bf16x8_t& hi, bf16x8_t& lo) {
    float v[8] = {a0.x, a0.y, a0.z, a0.w, a1.x, a1.y, a1.z, a1.w};
    union { short s[8]; bf16x8_t t; } H, L;
    #pragma unroll
    for (int i = 0; i < 8; ++i) {
        short h = f2bf(v[i]);
        H.s[i] = h;
        L.s[i] = f2bf(v[i] - bf2f(h));
    }
    hi = H.t; lo = L.t;
}
__device__ __forceinline__ void split8p(const float* p, bf16x8_t& hi, bf16x8_t& lo) {
    split8(*(const float4*)p, *(const float4*)(p + 4), hi, lo);
}

// ---------------- encoder: h = relu(X @ Wenc^T + benc) -----------------
__global__ __launch_bounds__(256) void encoder_k(
    const float* __restrict__ X, const float* __restrict__ Wenc,
    const float* __restrict__ benc, float* __restrict__ h,
    short* __restrict__ Ht)
{
    const int g = blockIdx.x * 256 + threadIdx.x;
    const int i = g >> 6, f = g & 63;
    const float4 x0 = *(const float4*)(X + i * 8);
    const float4 x1 = *(const float4*)(X + i * 8 + 4);
    const float4 w0 = *(const float4*)(Wenc + f * 8);
    const float4 w1 = *(const float4*)(Wenc + f * 8 + 4);
    float acc = benc[f]
              + x0.x * w0.x + x0.y * w0.y + x0.z * w0.z + x0.w * w0.w
              + x1.x * w1.x + x1.y * w1.y + x1.z * w1.z + x1.w * w1.w;
    acc = fmaxf(acc, 0.f);
    h[g] = acc;
    Ht[f * GN + i] = f2bf(acc);
}

// ---------------- GEMM: part[ks] = A[64-tile][kseg] @ h[kseg][64] -------
// Barrier-free: each lane loads its own MFMA fragments directly from global.
__global__ __launch_bounds__(256) void gemm_ah(
    const float* __restrict__ A, const short* __restrict__ Ht,
    float* __restrict__ part, int ks_len)
{
    const int t = threadIdx.x;
    const int w = t >> 6, lane = t & 63;
    const int quad = lane >> 4, l16 = lane & 15;
    const int m0 = (blockIdx.y << 6) + (w << 4);
    const int kb = blockIdx.x * ks_len;

    const float* aP = A  + (size_t)(m0 + l16) * GN + kb + quad * 8;
    const short* bP = Ht + (size_t)l16 * GN + kb + quad * 8;

    f32x4_t acc0 = {0.f, 0.f, 0.f, 0.f};
    f32x4_t acc1 = acc0, acc2 = acc0, acc3 = acc0;

    #pragma unroll 4
    for (int kk = 0; kk < ks_len; kk += 32) {
        float4   a0 = *(const float4*)(aP + kk);
        float4   a1 = *(const float4*)(aP + kk + 4);
        bf16x8_t b0 = *(const bf16x8_t*)(bP + kk);
        bf16x8_t b1 = *(const bf16x8_t*)(bP + kk + 16 * GN);
        bf16x8_t b2 = *(const bf16x8_t*)(bP + kk + 32 * GN);
        bf16x8_t b3 = *(const bf16x8_t*)(bP + kk + 48 * GN);
        bf16x8_t af = cvt8(a0, a1);
        acc0 = __builtin_amdgcn_mfma_f32_16x16x32_bf16(af, b0, acc0, 0, 0, 0);
        acc1 = __builtin_amdgcn_mfma_f32_16x16x32_bf16(af, b1, acc1, 0, 0, 0);
        acc2 = __builtin_amdgcn_mfma_f32_16x16x32_bf16(af, b2, acc2, 0, 0, 0);
        acc3 = __builtin_amdgcn_mfma_f32_16x16x32_bf16(af, b3, acc3, 0, 0, 0);
    }

    // C/D: m = quad*4 + r, n = nt*16 + l16
    float* o = part + ((size_t)blockIdx.x * GN + m0 + quad * 4) * 64 + l16;
    #pragma unroll
    for (int r = 0; r < 4; ++r) {
        o[r * 64 +  0] = acc0[r];
        o[r * 64 + 16] = acc1[r];
        o[r * 64 + 32] = acc2[r];
        o[r * 64 + 48] = acc3[r];
    }
}

// ------- dense: h = relu([h, sum part] @ W^T + b), split-bf16 MFMA ------
// hi/lo decomposition gives ~fp32 precision: a*b ~= ah*bh + ah*bl + al*bh.
__global__ __launch_bounds__(64) void dense_split(
    const float* __restrict__ hin, const float* __restrict__ part,
    const float* __restrict__ W, const float* __restrict__ bias,
    float* __restrict__ hout, short* __restrict__ HtOut)
{
    const int lane = threadIdx.x & 63;
    const int quad = lane >> 4, l16 = lane & 15;
    const int m0 = blockIdx.x << 4;

    f32x4_t acc0 = {0.f, 0.f, 0.f, 0.f};
    f32x4_t acc1 = acc0, acc2 = acc0, acc3 = acc0;

    #pragma unroll
    for (int half = 0; half < 2; ++half) {
        #pragma unroll
        for (int kk = 0; kk < 64; kk += 32) {
            const int kq = kk + quad * 8;
            bf16x8_t ah, al;
            if (half == 0) {
                split8p(hin + (size_t)(m0 + l16) * 64 + kq, ah, al);
            } else {
                const size_t base = (size_t)(m0 + l16) * 64 + kq;
                float4 s0 = make_float4(0.f, 0.f, 0.f, 0.f);
                float4 s1 = make_float4(0.f, 0.f, 0.f, 0.f);
                #pragma unroll
                for (int p = 0; p < KS; ++p) {
                    const float* pp = part + (size_t)p * (GN * 64) + base;
                    float4 v0 = *(const float4*)pp;
                    float4 v1 = *(const float4*)(pp + 4);
                    s0.x += v0.x; s0.y += v0.y; s0.z += v0.z; s0.w += v0.w;
                    s1.x += v1.x; s1.y += v1.y; s1.z += v1.z; s1.w += v1.w;
                }
                split8(s0, s1, ah, al);
            }
            const float* wp = W + half * 64 + kq;
            bf16x8_t bh0, bl0, bh1, bl1, bh2, bl2, bh3, bl3;
            split8p(wp + (size_t)(l16     ) * 128, bh0, bl0);
            split8p(wp + (size_t)(l16 + 16) * 128, bh1, bl1);
            split8p(wp + (size_t)(l16 + 32) * 128, bh2, bl2);
            split8p(wp + (size_t)(l16 + 48) * 128, bh3, bl3);
            acc0 = __builtin_amdgcn_mfma_f32_16x16x32_bf16(ah, bh0, acc0, 0, 0, 0);
            acc0 = __builtin_amdgcn_mfma_f32_16x16x32_bf16(ah, bl0, acc0, 0, 0, 0);
            acc0 = __builtin_amdgcn_mfma_f32_16x16x32_bf16(al, bh0, acc0, 0, 0, 0);
            acc1 = __builtin_amdgcn_mfma_f32_16x16x32_bf16(ah, bh1, acc1, 0, 0, 0);
            acc1 = __builtin_amdgcn_mfma_f32_16x16x32_bf16(ah, bl1, acc1, 0, 0, 0);
            acc1 = __builtin_amdgcn_mfma_f32_16x16x32_bf16(al, bh1, acc1, 0, 0, 0);
            acc2 = __builtin_amdgcn_mfma_f32_16x16x32_bf16(ah, bh2, acc2, 0, 0, 0);
            acc2 = __builtin_amdgcn_mfma_f32_16x16x32_bf16(ah, bl2, acc2, 0, 0, 0);
            acc2 = __builtin_amdgcn_mfma_f32_16x16x32_bf16(al, bh2, acc2, 0, 0, 0);
            acc3 = __builtin_amdgcn_mfma_f32_16x16x32_bf16(ah, bh3, acc3, 0, 0, 0);
            acc3 = __builtin_amdgcn_mfma_f32_16x16x32_bf16(ah, bl3, acc3, 0, 0, 0);
            acc3 = __builtin_amdgcn_mfma_f32_16x16x32_bf16(al, bh3, acc3, 0, 0, 0);
        }
    }

    const float bia0 = bias[l16], bia1 = bias[l16 + 16];
    const float bia2 = bias[l16 + 32], bia3 = bias[l16 + 48];
    #pragma unroll
    for (int r = 0; r < 4; ++r) {
        const int node = m0 + quad * 4 + r;
        float v0 = fmaxf(acc0[r] + bia0, 0.f);
        float v1 = fmaxf(acc1[r] + bia1, 0.f);
        float v2 = fmaxf(acc2[r] + bia2, 0.f);
        float v3 = fmaxf(acc3[r] + bia3, 0.f);
        float* hp = hout + (size_t)node * 64 + l16;
        hp[ 0] = v0; hp[16] = v1; hp[32] = v2; hp[48] = v3;
        HtOut[(size_t)(l16     ) * GN + node] = f2bf(v0);
        HtOut[(size_t)(l16 + 16) * GN + node] = f2bf(v1);
        HtOut[(size_t)(l16 + 32) * GN + node] = f2bf(v2);
        HtOut[(size_t)(l16 + 48) * GN + node] = f2bf(v3);
    }
}

// ---------------- edge projection: s_i = h@w_i, s_j = h@w_j -------------
__global__ __launch_bounds__(256) void edge_k(
    const float* __restrict__ h, const float* __restrict__ Wedge,
    float* __restrict__ s_i, float* __restrict__ s_j)
{
    const int t = threadIdx.x;
    const int node = blockIdx.x * 4 + (t >> 6);
    const int f = t & 63;
    const float hv = h[(size_t)node * 64 + f];
    float vi = hv * Wedge[f];
    float vj = hv * Wedge[64 + f];
    #pragma unroll
    for (int off = 32; off > 0; off >>= 1) {
        vi += __shfl_xor(vi, off, 64);
        vj += __shfl_xor(vj, off, 64);
    }
    if (f == 0) { s_i[node] = vi; s_j[node] = vj; }
}

// ---------------- scores: out[i][j] = s_i[i] + s_j[j] + be, diag 0 ------
__global__ __launch_bounds__(256) void scores_k(
    const float* __restrict__ s_i, const float* __restrict__ s_j,
    const float* __restrict__ be, float* __restrict__ out)
{
    const int i  = blockIdx.y;
    const int j0 = (blockIdx.x * 256 + threadIdx.x) * 4;
    const float si = s_i[i] + be[0];
    const float4 sj = *(const float4*)(s_j + j0);
    float4 o = make_float4(si + sj.x, si + sj.y, si + sj.z, si + sj.w);
    const int d = i - j0;
    if (d >= 0 && d < 4) (&o.x)[d] = 0.f;
    *(float4*)(out + (size_t)i * GN + j0) = o;
}

extern "C" void kernel_launch(void* const* d_in, const int* in_sizes, int n_in,
                              void* d_out, int out_size, void* d_ws, size_t ws_size,
                              hipStream_t stream) {
    const float* X     = (const float*)d_in[0];
    const float* A     = (const float*)d_in[1];
    const float* Wenc  = (const float*)d_in[2];
    const float* benc  = (const float*)d_in[3];
    const float* Wmat[3] = {(const float*)d_in[4], (const float*)d_in[6], (const float*)d_in[8]};
    const float* bvec[3] = {(const float*)d_in[5], (const float*)d_in[7], (const float*)d_in[9]};
    const float* Wedge = (const float*)d_in[10];
    const float* bedge = (const float*)d_in[11];
    float* out = (float*)d_out;

    char* ws = (char*)d_ws;
    float* part = (float*)ws;                                   // KS*4096*64 f32 = 8 MiB
    float* h    = (float*)(ws + ((size_t)8 << 20));             // 1 MiB
    short* Ht   = (short*)(ws + ((size_t)9 << 20));             // 0.5 MiB
    float* s_i  = (float*)(ws + ((size_t)9 << 20) + (512u << 10));
    float* s_j  = s_i + GN;

    encoder_k<<<dim3(GN * 64 / 256), 256, 0, stream>>>(X, Wenc, benc, h, Ht);

    for (int r = 0; r < 3; ++r) {
        gemm_ah<<<dim3(KS, GN / 64), 256, 0, stream>>>(A, Ht, part, GN / KS);
        dense_split<<<dim3(GN / 16), 64, 0, stream>>>(
            h, part, Wmat[r], bvec[r], h, Ht);
    }

    edge_k<<<dim3(GN / 4), 256, 0, stream>>>(h, Wedge, s_i, s_j);
    scores_k<<<dim3(GN / 1024, GN), 256, 0, stream>>>(s_i, s_j, bedge, out);
}